// Round 3
// baseline (1477.633 us; speedup 1.0000x reference)
//
#include <hip/hip_runtime.h>

#define NUM_USER 50000
#define NUM_ITEM 25000
#define N_NODES 75000
#define DIM 64
#define N_INTENTS 128
#define N_EDGES 800000

// ---------------- CSR build ----------------

__global__ __launch_bounds__(256) void zero_cnt_kernel(int* __restrict__ cnt, int n) {
  int i = blockIdx.x * 256 + threadIdx.x;
  if (i < n) cnt[i] = 0;
}

__global__ __launch_bounds__(256) void count_kernel(const int* __restrict__ h, const int* __restrict__ t,
                                                    int* __restrict__ cnt) {
  int e = blockIdx.x * 256 + threadIdx.x;
  if (e >= N_EDGES) return;
  atomicAdd(&cnt[h[e]], 1);
  atomicAdd(&cnt[t[e]], 1);
}

// Single-block exclusive scan over n=75000 counts; also emits cursor copy and dinv.
__global__ __launch_bounds__(1024) void scan_kernel(const int* __restrict__ cnt, int* __restrict__ off,
                                                    int* __restrict__ cursor, float* __restrict__ dinv, int n) {
  __shared__ int wsum[16];
  __shared__ int carry_s;
  int tid = threadIdx.x, lane = tid & 63, wid = tid >> 6;
  if (tid == 0) carry_s = 0;
  __syncthreads();
  for (int base = 0; base < n; base += 1024) {
    int idx = base + tid;
    int orig = (idx < n) ? cnt[idx] : 0;
    int v = orig;
#pragma unroll
    for (int d = 1; d < 64; d <<= 1) {
      int u = __shfl_up(v, d, 64);
      if (lane >= d) v += u;
    }
    if (lane == 63) wsum[wid] = v;
    __syncthreads();
    if (tid == 0) {
      int run = carry_s;
#pragma unroll
      for (int i = 0; i < 16; i++) { int tmp = wsum[i]; wsum[i] = run; run += tmp; }
      carry_s = run;
    }
    __syncthreads();
    if (idx < n) {
      int excl = wsum[wid] + v - orig;
      off[idx] = excl;
      cursor[idx] = excl;
      dinv[idx] = rsqrtf((float)orig + 1e-7f);
    }
    __syncthreads();
  }
  if (tid == 0) off[n] = carry_s;
}

__global__ __launch_bounds__(256) void fill_kernel(const int* __restrict__ h, const int* __restrict__ t,
                                                   int* __restrict__ cursor, int* __restrict__ colarr) {
  int e = blockIdx.x * 256 + threadIdx.x;
  if (e >= N_EDGES) return;
  int hv = h[e], tv = t[e];
  int p1 = atomicAdd(&cursor[hv], 1);
  colarr[p1] = tv;
  int p2 = atomicAdd(&cursor[tv], 1);
  colarr[p2] = hv;
}

__global__ __launch_bounds__(256) void xinit_kernel(float4* __restrict__ x, const float4* __restrict__ ue,
                                                    const float4* __restrict__ ie) {
  int i = blockIdx.x * 256 + threadIdx.x;
  if (i >= N_NODES * 16) return;
  x[i] = (i < NUM_USER * 16) ? ue[i] : ie[i - NUM_USER * 16];
}

// ---------------- Per-layer kernels ----------------

// gnn[row] = dinv[row] * sum_c dinv[c] * x[c]; also invn_g[row] = 1/max(||gnn[row]||,1e-12)
// 16 lanes per row, float4 per lane (64 floats = one embedding row per 16-lane group).
__global__ __launch_bounds__(256) void spmm_kernel(const int* __restrict__ off, const int* __restrict__ colarr,
                                                   const float* __restrict__ dinv, const float* __restrict__ x,
                                                   float* __restrict__ gnn, float* __restrict__ invn) {
  int tid = threadIdx.x;
  int row = blockIdx.x * 16 + (tid >> 4);
  int sub = tid & 15;
  if (row >= N_NODES) return;
  int s = off[row], e = off[row + 1];
  const float4* x4 = (const float4*)x;
  float4 acc = make_float4(0.f, 0.f, 0.f, 0.f);
  for (int i = s; i < e; i++) {
    int c = colarr[i];
    float w = dinv[c];
    float4 xv = x4[c * 16 + sub];
    acc.x = fmaf(w, xv.x, acc.x);
    acc.y = fmaf(w, xv.y, acc.y);
    acc.z = fmaf(w, xv.z, acc.z);
    acc.w = fmaf(w, xv.w, acc.w);
  }
  float dr = dinv[row];
  acc.x *= dr; acc.y *= dr; acc.z *= dr; acc.w *= dr;
  ((float4*)gnn)[row * 16 + sub] = acc;
  float ss = acc.x * acc.x + acc.y * acc.y + acc.z * acc.z + acc.w * acc.w;
  ss += __shfl_xor(ss, 1); ss += __shfl_xor(ss, 2);
  ss += __shfl_xor(ss, 4); ss += __shfl_xor(ss, 8);
  if (sub == 0) invn[row] = 1.f / fmaxf(sqrtf(ss), 1e-12f);
}

// intl[row] = softmax(x[row] @ W) @ W^T  (W is 64x128), plus invn.
// W held LDS-swizzled so both access patterns (lane=intent in scores, lane=dim in
// projection) are conflict-light. Intra-wave LDS write->read (ps) needs no barrier
// on CDNA (same-wave LDS ops are in order).
__global__ __launch_bounds__(256) void intent_kernel(const float* __restrict__ x, const float* __restrict__ W,
                                                     float* __restrict__ outl, float* __restrict__ invn,
                                                     int row_base, int n_rows) {
  __shared__ float WT[N_INTENTS * DIM];  // WT[j*64 + (d ^ (j&31))] = W[d*128 + j]
  __shared__ float ps[4][N_INTENTS];
  int tid = threadIdx.x;
  for (int i = tid; i < DIM * N_INTENTS; i += 256) {
    int d = i >> 7, j = i & 127;
    WT[j * 64 + (d ^ (j & 31))] = W[i];
  }
  __syncthreads();
  int wid = tid >> 6, lane = tid & 63;
  int sw = lane & 31;
  for (int r = blockIdx.x * 4 + wid; r < n_rows; r += gridDim.x * 4) {
    int row = row_base + r;
    float e = x[(size_t)row * 64 + lane];
    float s0 = 0.f, s1 = 0.f;
#pragma unroll
    for (int l = 0; l < 64; l++) {
      float el = __shfl(e, l, 64);
      s0 = fmaf(el, WT[lane * 64 + (l ^ sw)], s0);
      s1 = fmaf(el, WT[(lane + 64) * 64 + (l ^ sw)], s1);  // (lane+64)&31 == lane&31
    }
    float m = fmaxf(s0, s1);
#pragma unroll
    for (int d = 32; d; d >>= 1) m = fmaxf(m, __shfl_xor(m, d));
    float p0 = expf(s0 - m), p1 = expf(s1 - m);
    float sum = p0 + p1;
#pragma unroll
    for (int d = 32; d; d >>= 1) sum += __shfl_xor(sum, d);
    float inv = 1.f / sum;
    ps[wid][lane] = p0 * inv;
    ps[wid][lane + 64] = p1 * inv;
    float acc = 0.f;
#pragma unroll
    for (int j = 0; j < 128; j++) {
      acc = fmaf(ps[wid][j], WT[j * 64 + (lane ^ (j & 31))], acc);
    }
    outl[(size_t)row * 64 + lane] = acc;
    float ss = acc * acc;
#pragma unroll
    for (int d = 32; d; d >>= 1) ss += __shfl_xor(ss, d);
    if (lane == 0) invn[row] = 1.f / fmaxf(sqrtf(ss), 1e-12f);
  }
}

// Fused gaa+iaa: for user rows, per neighbor c compute both alphas (cosine of gnn
// rows, cosine of intl rows) and accumulate alpha*x[c] — pays the x[c] gather once
// for both outputs. Item rows are zero (reference segment-sums over h_idx only).
// NOTE: must NOT also update x here — other blocks still read x[c].
__global__ __launch_bounds__(256) void adaptive2_kernel(const int* __restrict__ off, const int* __restrict__ colarr,
                                                        const float* __restrict__ gnn, const float* __restrict__ invg,
                                                        const float* __restrict__ intl, const float* __restrict__ invi,
                                                        const float* __restrict__ x,
                                                        float* __restrict__ gaa, float* __restrict__ iaa) {
  int tid = threadIdx.x;
  int row = blockIdx.x * 16 + (tid >> 4);
  int sub = tid & 15;
  if (row >= N_NODES) return;
  float4 z = make_float4(0.f, 0.f, 0.f, 0.f);
  if (row >= NUM_USER) {
    ((float4*)gaa)[row * 16 + sub] = z;
    ((float4*)iaa)[row * 16 + sub] = z;
    return;
  }
  const float4* g4 = (const float4*)gnn;
  const float4* i4 = (const float4*)intl;
  const float4* x4 = (const float4*)x;
  float4 eg = g4[row * 16 + sub];
  float4 ei = i4[row * 16 + sub];
  float ug = invg[row], ui = invi[row];
  int s = off[row], e = off[row + 1];
  float4 ag = z, ai = z;
  for (int i = s; i < e; i++) {
    int c = colarr[i];
    float4 gt = g4[c * 16 + sub];
    float4 it = i4[c * 16 + sub];
    float dg = eg.x * gt.x + eg.y * gt.y + eg.z * gt.z + eg.w * gt.w;
    float di = ei.x * it.x + ei.y * it.y + ei.z * it.z + ei.w * it.w;
    dg += __shfl_xor(dg, 1); dg += __shfl_xor(dg, 2); dg += __shfl_xor(dg, 4); dg += __shfl_xor(dg, 8);
    di += __shfl_xor(di, 1); di += __shfl_xor(di, 2); di += __shfl_xor(di, 4); di += __shfl_xor(di, 8);
    float alg = fmaf(dg * ug * invg[c], 0.5f, 0.5f);
    float ali = fmaf(di * ui * invi[c], 0.5f, 0.5f);
    float4 xv = x4[c * 16 + sub];
    ag.x = fmaf(alg, xv.x, ag.x); ag.y = fmaf(alg, xv.y, ag.y);
    ag.z = fmaf(alg, xv.z, ag.z); ag.w = fmaf(alg, xv.w, ag.w);
    ai.x = fmaf(ali, xv.x, ai.x); ai.y = fmaf(ali, xv.y, ai.y);
    ai.z = fmaf(ali, xv.z, ai.z); ai.w = fmaf(ali, xv.w, ai.w);
  }
  ((float4*)gaa)[row * 16 + sub] = ag;
  ((float4*)iaa)[row * 16 + sub] = ai;
}

__global__ __launch_bounds__(256) void xupd_kernel(float* __restrict__ x, const float4* __restrict__ a,
                                                   const float4* __restrict__ b, const float4* __restrict__ c,
                                                   const float4* __restrict__ d) {
  int i = blockIdx.x * 256 + threadIdx.x;
  if (i >= N_NODES * 16) return;
  float4* x4 = (float4*)x;
  float4 v = x4[i], va = a[i], vb = b[i], vc = c[i], vd = d[i];
  v.x += va.x + vb.x + vc.x + vd.x;
  v.y += va.y + vb.y + vc.y + vd.y;
  v.z += va.z + vb.z + vc.z + vd.z;
  v.w += va.w + vb.w + vc.w + vd.w;
  x4[i] = v;
}

// ---------------- Host launcher ----------------

extern "C" void kernel_launch(void* const* d_in, const int* in_sizes, int n_in,
                              void* d_out, int out_size, void* d_ws, size_t ws_size,
                              hipStream_t stream) {
  const float* user_emb = (const float*)d_in[0];
  const float* item_emb = (const float*)d_in[1];
  const float* user_intent = (const float*)d_in[2];
  const float* item_intent = (const float*)d_in[3];
  const int* h_idx = (const int*)d_in[4];
  const int* t_idx = (const int*)d_in[5];
  float* out = (float*)d_out;

  char* p = (char*)d_ws;
  auto alloc = [&](size_t bytes) {
    char* r = p;
    p += (bytes + 255) & ~(size_t)255;
    return r;
  };
  int* cnt = (int*)alloc((size_t)N_NODES * 4);
  int* off = (int*)alloc((size_t)(N_NODES + 1) * 4);
  int* cursor = (int*)alloc((size_t)N_NODES * 4);
  float* dinv = (float*)alloc((size_t)N_NODES * 4);
  float* invn_g = (float*)alloc((size_t)N_NODES * 4);
  float* invn_i = (float*)alloc((size_t)N_NODES * 4);
  int* colarr = (int*)alloc((size_t)2 * N_EDGES * 4);
  float* x = (float*)alloc((size_t)N_NODES * DIM * 4);

  hipLaunchKernelGGL(zero_cnt_kernel, dim3((N_NODES + 255) / 256), dim3(256), 0, stream, cnt, N_NODES);
  hipLaunchKernelGGL(count_kernel, dim3((N_EDGES + 255) / 256), dim3(256), 0, stream, h_idx, t_idx, cnt);
  hipLaunchKernelGGL(scan_kernel, dim3(1), dim3(1024), 0, stream, cnt, off, cursor, dinv, N_NODES);
  hipLaunchKernelGGL(fill_kernel, dim3((N_EDGES + 255) / 256), dim3(256), 0, stream, h_idx, t_idx, cursor, colarr);
  hipLaunchKernelGGL(xinit_kernel, dim3((N_NODES * 16 + 255) / 256), dim3(256), 0, stream,
                     (float4*)x, (const float4*)user_emb, (const float4*)item_emb);

  const size_t SL = (size_t)N_NODES * DIM;
  for (int layer = 0; layer < 2; layer++) {
    float* gnn = out + (0 * 2 + layer) * SL;
    float* intl = out + (1 * 2 + layer) * SL;
    float* gaa = out + (2 * 2 + layer) * SL;
    float* iaa = out + (3 * 2 + layer) * SL;

    hipLaunchKernelGGL(spmm_kernel, dim3((N_NODES + 15) / 16), dim3(256), 0, stream,
                       off, colarr, dinv, x, gnn, invn_g);
    hipLaunchKernelGGL(intent_kernel, dim3(2048), dim3(256), 0, stream,
                       x, user_intent, intl, invn_i, 0, NUM_USER);
    hipLaunchKernelGGL(intent_kernel, dim3(1024), dim3(256), 0, stream,
                       x, item_intent, intl, invn_i, NUM_USER, NUM_ITEM);
    hipLaunchKernelGGL(adaptive2_kernel, dim3((N_NODES + 15) / 16), dim3(256), 0, stream,
                       off, colarr, gnn, invn_g, intl, invn_i, x, gaa, iaa);
    if (layer == 0) {
      hipLaunchKernelGGL(xupd_kernel, dim3((N_NODES * 16 + 255) / 256), dim3(256), 0, stream,
                         x, (const float4*)gnn, (const float4*)intl, (const float4*)gaa, (const float4*)iaa);
    }
  }
}

// Round 4
// 1038.046 us; speedup vs baseline: 1.4235x; 1.4235x over previous
//
#include <hip/hip_runtime.h>

#define NUM_USER 50000
#define NUM_ITEM 25000
#define N_NODES 75000
#define DIM 64
#define N_INTENTS 128
#define N_EDGES 800000

// ---------------- CSR build ----------------

__global__ __launch_bounds__(256) void zero_cnt_kernel(int* __restrict__ cnt, int n) {
  int i = blockIdx.x * 256 + threadIdx.x;
  if (i < n) cnt[i] = 0;
}

__global__ __launch_bounds__(256) void count_kernel(const int* __restrict__ h, const int* __restrict__ t,
                                                    int* __restrict__ cnt) {
  int e = blockIdx.x * 256 + threadIdx.x;
  if (e >= N_EDGES) return;
  atomicAdd(&cnt[h[e]], 1);
  atomicAdd(&cnt[t[e]], 1);
}

// Single-block exclusive scan over n=75000 counts; also emits cursor copy and dinv.
__global__ __launch_bounds__(1024) void scan_kernel(const int* __restrict__ cnt, int* __restrict__ off,
                                                    int* __restrict__ cursor, float* __restrict__ dinv, int n) {
  __shared__ int wsum[16];
  __shared__ int carry_s;
  int tid = threadIdx.x, lane = tid & 63, wid = tid >> 6;
  if (tid == 0) carry_s = 0;
  __syncthreads();
  for (int base = 0; base < n; base += 1024) {
    int idx = base + tid;
    int orig = (idx < n) ? cnt[idx] : 0;
    int v = orig;
#pragma unroll
    for (int d = 1; d < 64; d <<= 1) {
      int u = __shfl_up(v, d, 64);
      if (lane >= d) v += u;
    }
    if (lane == 63) wsum[wid] = v;
    __syncthreads();
    if (tid == 0) {
      int run = carry_s;
#pragma unroll
      for (int i = 0; i < 16; i++) { int tmp = wsum[i]; wsum[i] = run; run += tmp; }
      carry_s = run;
    }
    __syncthreads();
    if (idx < n) {
      int excl = wsum[wid] + v - orig;
      off[idx] = excl;
      cursor[idx] = excl;
      dinv[idx] = rsqrtf((float)orig + 1e-7f);
    }
    __syncthreads();
  }
  if (tid == 0) off[n] = carry_s;
}

__global__ __launch_bounds__(256) void fill_kernel(const int* __restrict__ h, const int* __restrict__ t,
                                                   int* __restrict__ cursor, int* __restrict__ colarr) {
  int e = blockIdx.x * 256 + threadIdx.x;
  if (e >= N_EDGES) return;
  int hv = h[e], tv = t[e];
  int p1 = atomicAdd(&cursor[hv], 1);
  colarr[p1] = tv;
  int p2 = atomicAdd(&cursor[tv], 1);
  colarr[p2] = hv;
}

__global__ __launch_bounds__(256) void xinit_kernel(float4* __restrict__ x, const float4* __restrict__ ue,
                                                    const float4* __restrict__ ie) {
  int i = blockIdx.x * 256 + threadIdx.x;
  if (i >= N_NODES * 16) return;
  x[i] = (i < NUM_USER * 16) ? ue[i] : ie[i - NUM_USER * 16];
}

// ---------------- Per-layer kernels ----------------

// gnn[row] = dinv[row] * sum_c dinv[c] * x[c]; also invn_g[row] = 1/max(||gnn[row]||,1e-12)
__global__ __launch_bounds__(256) void spmm_kernel(const int* __restrict__ off, const int* __restrict__ colarr,
                                                   const float* __restrict__ dinv, const float* __restrict__ x,
                                                   float* __restrict__ gnn, float* __restrict__ invn) {
  int tid = threadIdx.x;
  int row = blockIdx.x * 16 + (tid >> 4);
  int sub = tid & 15;
  if (row >= N_NODES) return;
  int s = off[row], e = off[row + 1];
  const float4* x4 = (const float4*)x;
  float4 acc = make_float4(0.f, 0.f, 0.f, 0.f);
  for (int i = s; i < e; i++) {
    int c = colarr[i];
    float w = dinv[c];
    float4 xv = x4[c * 16 + sub];
    acc.x = fmaf(w, xv.x, acc.x);
    acc.y = fmaf(w, xv.y, acc.y);
    acc.z = fmaf(w, xv.z, acc.z);
    acc.w = fmaf(w, xv.w, acc.w);
  }
  float dr = dinv[row];
  acc.x *= dr; acc.y *= dr; acc.z *= dr; acc.w *= dr;
  ((float4*)gnn)[row * 16 + sub] = acc;
  float ss = acc.x * acc.x + acc.y * acc.y + acc.z * acc.z + acc.w * acc.w;
  ss += __shfl_xor(ss, 1); ss += __shfl_xor(ss, 2);
  ss += __shfl_xor(ss, 4); ss += __shfl_xor(ss, 8);
  if (sub == 0) invn[row] = 1.f / fmaxf(sqrtf(ss), 1e-12f);
}

// intl[row] = softmax(x[row] @ W) @ W^T for all 75000 rows in ONE dispatch.
// Structure (round-3 redesign, fixing the 17%-VALUBusy latency-bound wave-per-row
// version): one ROW PER LANE, row in 16 float4 VGPRs, W^T staged in LDS and read
// as wave-uniform broadcast ds_read_b128 (conflict-free). Zero cross-lane ops.
// Softmax: pass1 = row max; pass2 = unnormalized accumulate out += e_j * W[:,j]
// with l += e_j; epilogue scales by 1/l. Scores recomputed in pass2 (bitwise
// identical arithmetic, so exp(0)=1 guarantees l>=1).
__global__ __launch_bounds__(256) void intent_kernel(const float* __restrict__ x,
                                                     const float* __restrict__ Wu,
                                                     const float* __restrict__ Wi,
                                                     float* __restrict__ outl, float* __restrict__ invn) {
  // Wc4[j*16 + (q ^ (j&7))] = float4{W[4q..4q+3][j]}  (swizzle breaks the 32-way
  // LDS *write* conflict during staging; reads are uniform-broadcast, swizzle-agnostic)
  __shared__ float Wc[N_INTENTS * DIM];
  const int UT = (NUM_USER + 255) / 256;  // 196 user tiles
  int b = blockIdx.x;
  const float* W;
  int row0, rend;
  if (b < UT) { W = Wu; row0 = b * 256; rend = NUM_USER; }
  else        { W = Wi; row0 = NUM_USER + (b - UT) * 256; rend = N_NODES; }
  int tid = threadIdx.x;
  for (int i = tid; i < DIM * N_INTENTS; i += 256) {
    int d = i >> 7, j = i & 127;          // coalesced read of W[d][j]
    int q = d >> 2, sub = d & 3;
    Wc[(j * 16 + (q ^ (j & 7))) * 4 + sub] = W[i];
  }
  __syncthreads();
  const float4* Wc4 = (const float4*)Wc;

  int row = row0 + tid;
  bool active = row < rend;
  const float4* x4 = (const float4*)x;
  float4 xr[16];
#pragma unroll
  for (int q = 0; q < 16; q++)
    xr[q] = active ? x4[(size_t)row * 16 + q] : make_float4(0.f, 0.f, 0.f, 0.f);

  // ---- pass 1: m = max_j s_j ----
  float m = -3.0e38f;
  for (int j = 0; j < N_INTENTS; j++) {
    const float4* wj = &Wc4[j * 16];
    int sw = j & 7;
    float s0 = 0.f, s1 = 0.f, s2 = 0.f, s3 = 0.f;
#pragma unroll
    for (int q = 0; q < 16; q += 4) {
      float4 a0 = xr[q],     w0 = wj[q ^ sw];
      float4 a1 = xr[q + 1], w1 = wj[(q + 1) ^ sw];
      float4 a2 = xr[q + 2], w2 = wj[(q + 2) ^ sw];
      float4 a3 = xr[q + 3], w3 = wj[(q + 3) ^ sw];
      s0 = fmaf(a0.x, w0.x, s0); s0 = fmaf(a0.y, w0.y, s0); s0 = fmaf(a0.z, w0.z, s0); s0 = fmaf(a0.w, w0.w, s0);
      s1 = fmaf(a1.x, w1.x, s1); s1 = fmaf(a1.y, w1.y, s1); s1 = fmaf(a1.z, w1.z, s1); s1 = fmaf(a1.w, w1.w, s1);
      s2 = fmaf(a2.x, w2.x, s2); s2 = fmaf(a2.y, w2.y, s2); s2 = fmaf(a2.z, w2.z, s2); s2 = fmaf(a2.w, w2.w, s2);
      s3 = fmaf(a3.x, w3.x, s3); s3 = fmaf(a3.y, w3.y, s3); s3 = fmaf(a3.z, w3.z, s3); s3 = fmaf(a3.w, w3.w, s3);
    }
    m = fmaxf(m, (s0 + s1) + (s2 + s3));
  }

  // ---- pass 2: l = sum e_j; o = sum e_j * W[:,j] ----
  float l = 0.f;
  float4 o[16];
#pragma unroll
  for (int q = 0; q < 16; q++) o[q] = make_float4(0.f, 0.f, 0.f, 0.f);
  for (int j = 0; j < N_INTENTS; j++) {
    const float4* wj = &Wc4[j * 16];
    int sw = j & 7;
    float4 w[16];
#pragma unroll
    for (int q = 0; q < 16; q++) w[q] = wj[q ^ sw];
    float s0 = 0.f, s1 = 0.f, s2 = 0.f, s3 = 0.f;
#pragma unroll
    for (int q = 0; q < 16; q += 4) {
      float4 a0 = xr[q], a1 = xr[q + 1], a2 = xr[q + 2], a3 = xr[q + 3];
      s0 = fmaf(a0.x, w[q].x, s0); s0 = fmaf(a0.y, w[q].y, s0); s0 = fmaf(a0.z, w[q].z, s0); s0 = fmaf(a0.w, w[q].w, s0);
      s1 = fmaf(a1.x, w[q+1].x, s1); s1 = fmaf(a1.y, w[q+1].y, s1); s1 = fmaf(a1.z, w[q+1].z, s1); s1 = fmaf(a1.w, w[q+1].w, s1);
      s2 = fmaf(a2.x, w[q+2].x, s2); s2 = fmaf(a2.y, w[q+2].y, s2); s2 = fmaf(a2.z, w[q+2].z, s2); s2 = fmaf(a2.w, w[q+2].w, s2);
      s3 = fmaf(a3.x, w[q+3].x, s3); s3 = fmaf(a3.y, w[q+3].y, s3); s3 = fmaf(a3.z, w[q+3].z, s3); s3 = fmaf(a3.w, w[q+3].w, s3);
    }
    float e = expf(((s0 + s1) + (s2 + s3)) - m);
    l += e;
#pragma unroll
    for (int q = 0; q < 16; q++) {
      o[q].x = fmaf(e, w[q].x, o[q].x);
      o[q].y = fmaf(e, w[q].y, o[q].y);
      o[q].z = fmaf(e, w[q].z, o[q].z);
      o[q].w = fmaf(e, w[q].w, o[q].w);
    }
  }

  // ---- epilogue: scale by 1/l, store, row norm ----
  if (!active) return;
  float invl = 1.f / l;  // l >= 1 (exact recompute: max column gives e=1)
  float ss = 0.f;
  float4* out4 = (float4*)outl;
#pragma unroll
  for (int q = 0; q < 16; q++) {
    float4 v = o[q];
    v.x *= invl; v.y *= invl; v.z *= invl; v.w *= invl;
    ss = fmaf(v.x, v.x, fmaf(v.y, v.y, fmaf(v.z, v.z, fmaf(v.w, v.w, ss))));
    out4[(size_t)row * 16 + q] = v;
  }
  invn[row] = 1.f / fmaxf(sqrtf(ss), 1e-12f);
}

// Fused gaa+iaa: for user rows, per neighbor c compute both alphas and accumulate
// alpha*x[c]. Item rows are zero (reference segment-sums over h_idx only).
__global__ __launch_bounds__(256) void adaptive2_kernel(const int* __restrict__ off, const int* __restrict__ colarr,
                                                        const float* __restrict__ gnn, const float* __restrict__ invg,
                                                        const float* __restrict__ intl, const float* __restrict__ invi,
                                                        const float* __restrict__ x,
                                                        float* __restrict__ gaa, float* __restrict__ iaa) {
  int tid = threadIdx.x;
  int row = blockIdx.x * 16 + (tid >> 4);
  int sub = tid & 15;
  if (row >= N_NODES) return;
  float4 z = make_float4(0.f, 0.f, 0.f, 0.f);
  if (row >= NUM_USER) {
    ((float4*)gaa)[row * 16 + sub] = z;
    ((float4*)iaa)[row * 16 + sub] = z;
    return;
  }
  const float4* g4 = (const float4*)gnn;
  const float4* i4 = (const float4*)intl;
  const float4* x4 = (const float4*)x;
  float4 eg = g4[row * 16 + sub];
  float4 ei = i4[row * 16 + sub];
  float ug = invg[row], ui = invi[row];
  int s = off[row], e = off[row + 1];
  float4 ag = z, ai = z;
  for (int i = s; i < e; i++) {
    int c = colarr[i];
    float4 gt = g4[c * 16 + sub];
    float4 it = i4[c * 16 + sub];
    float dg = eg.x * gt.x + eg.y * gt.y + eg.z * gt.z + eg.w * gt.w;
    float di = ei.x * it.x + ei.y * it.y + ei.z * it.z + ei.w * it.w;
    dg += __shfl_xor(dg, 1); dg += __shfl_xor(dg, 2); dg += __shfl_xor(dg, 4); dg += __shfl_xor(dg, 8);
    di += __shfl_xor(di, 1); di += __shfl_xor(di, 2); di += __shfl_xor(di, 4); di += __shfl_xor(di, 8);
    float alg = fmaf(dg * ug * invg[c], 0.5f, 0.5f);
    float ali = fmaf(di * ui * invi[c], 0.5f, 0.5f);
    float4 xv = x4[c * 16 + sub];
    ag.x = fmaf(alg, xv.x, ag.x); ag.y = fmaf(alg, xv.y, ag.y);
    ag.z = fmaf(alg, xv.z, ag.z); ag.w = fmaf(alg, xv.w, ag.w);
    ai.x = fmaf(ali, xv.x, ai.x); ai.y = fmaf(ali, xv.y, ai.y);
    ai.z = fmaf(ali, xv.z, ai.z); ai.w = fmaf(ali, xv.w, ai.w);
  }
  ((float4*)gaa)[row * 16 + sub] = ag;
  ((float4*)iaa)[row * 16 + sub] = ai;
}

__global__ __launch_bounds__(256) void xupd_kernel(float* __restrict__ x, const float4* __restrict__ a,
                                                   const float4* __restrict__ b, const float4* __restrict__ c,
                                                   const float4* __restrict__ d) {
  int i = blockIdx.x * 256 + threadIdx.x;
  if (i >= N_NODES * 16) return;
  float4* x4 = (float4*)x;
  float4 v = x4[i], va = a[i], vb = b[i], vc = c[i], vd = d[i];
  v.x += va.x + vb.x + vc.x + vd.x;
  v.y += va.y + vb.y + vc.y + vd.y;
  v.z += va.z + vb.z + vc.z + vd.z;
  v.w += va.w + vb.w + vc.w + vd.w;
  x4[i] = v;
}

// ---------------- Host launcher ----------------

extern "C" void kernel_launch(void* const* d_in, const int* in_sizes, int n_in,
                              void* d_out, int out_size, void* d_ws, size_t ws_size,
                              hipStream_t stream) {
  const float* user_emb = (const float*)d_in[0];
  const float* item_emb = (const float*)d_in[1];
  const float* user_intent = (const float*)d_in[2];
  const float* item_intent = (const float*)d_in[3];
  const int* h_idx = (const int*)d_in[4];
  const int* t_idx = (const int*)d_in[5];
  float* out = (float*)d_out;

  char* p = (char*)d_ws;
  auto alloc = [&](size_t bytes) {
    char* r = p;
    p += (bytes + 255) & ~(size_t)255;
    return r;
  };
  int* cnt = (int*)alloc((size_t)N_NODES * 4);
  int* off = (int*)alloc((size_t)(N_NODES + 1) * 4);
  int* cursor = (int*)alloc((size_t)N_NODES * 4);
  float* dinv = (float*)alloc((size_t)N_NODES * 4);
  float* invn_g = (float*)alloc((size_t)N_NODES * 4);
  float* invn_i = (float*)alloc((size_t)N_NODES * 4);
  int* colarr = (int*)alloc((size_t)2 * N_EDGES * 4);
  float* x = (float*)alloc((size_t)N_NODES * DIM * 4);

  hipLaunchKernelGGL(zero_cnt_kernel, dim3((N_NODES + 255) / 256), dim3(256), 0, stream, cnt, N_NODES);
  hipLaunchKernelGGL(count_kernel, dim3((N_EDGES + 255) / 256), dim3(256), 0, stream, h_idx, t_idx, cnt);
  hipLaunchKernelGGL(scan_kernel, dim3(1), dim3(1024), 0, stream, cnt, off, cursor, dinv, N_NODES);
  hipLaunchKernelGGL(fill_kernel, dim3((N_EDGES + 255) / 256), dim3(256), 0, stream, h_idx, t_idx, cursor, colarr);
  hipLaunchKernelGGL(xinit_kernel, dim3((N_NODES * 16 + 255) / 256), dim3(256), 0, stream,
                     (float4*)x, (const float4*)user_emb, (const float4*)item_emb);

  const int UT = (NUM_USER + 255) / 256;        // 196
  const int IT = (NUM_ITEM + 255) / 256;        // 98
  const size_t SL = (size_t)N_NODES * DIM;
  for (int layer = 0; layer < 2; layer++) {
    float* gnn = out + (0 * 2 + layer) * SL;
    float* intl = out + (1 * 2 + layer) * SL;
    float* gaa = out + (2 * 2 + layer) * SL;
    float* iaa = out + (3 * 2 + layer) * SL;

    hipLaunchKernelGGL(spmm_kernel, dim3((N_NODES + 15) / 16), dim3(256), 0, stream,
                       off, colarr, dinv, x, gnn, invn_g);
    hipLaunchKernelGGL(intent_kernel, dim3(UT + IT), dim3(256), 0, stream,
                       x, user_intent, item_intent, intl, invn_i);
    hipLaunchKernelGGL(adaptive2_kernel, dim3((N_NODES + 15) / 16), dim3(256), 0, stream,
                       off, colarr, gnn, invn_g, intl, invn_i, x, gaa, iaa);
    if (layer == 0) {
      hipLaunchKernelGGL(xupd_kernel, dim3((N_NODES * 16 + 255) / 256), dim3(256), 0, stream,
                         x, (const float4*)gnn, (const float4*)intl, (const float4*)gaa, (const float4*)iaa);
    }
  }
}